// Round 22
// baseline (235.693 us; speedup 1.0000x reference)
//
#include <hip/hip_runtime.h>
#include <hip/hip_bf16.h>
#include <hip/hip_fp8.h>
#include <math.h>

typedef __attribute__((ext_vector_type(4))) float f32x4;

#define NB 4096
#define ND 1024
#define INV_T 14.2857142857142857f   // 1/0.07

__device__ inline float fp82f(unsigned char b) {
    __hip_fp8_e4m3 h; h.__x = b;
    return (float)h;
}
__device__ inline void gload16(const void* g, void* l) {
    __builtin_amdgcn_global_load_lds(
        (const __attribute__((address_space(1))) void*)g,
        (__attribute__((address_space(3))) void*)l, 16, 0, 0);
}

// ---------------- kernel 0: L2-normalize rows, cast to fp8 e4m3 -------------
__global__ __launch_bounds__(256) void norm_kernel(
        const float* __restrict__ M, const float* __restrict__ P,
        unsigned char* __restrict__ Mf, unsigned char* __restrict__ Pf) {
    int row = blockIdx.x & (NB - 1);
    const float* src = (blockIdx.x < NB) ? M : P;
    unsigned char* dst = (blockIdx.x < NB) ? Mf : Pf;
    int tid = threadIdx.x;
    float4 v = ((const float4*)(src + (size_t)row * ND))[tid];
    float ss = v.x * v.x + v.y * v.y + v.z * v.z + v.w * v.w;
    for (int off = 32; off; off >>= 1) ss += __shfl_down(ss, off);
    __shared__ float red[4];
    int lane = tid & 63, w = tid >> 6;
    if (lane == 0) red[w] = ss;
    __syncthreads();
    float rn = rsqrtf(red[0] + red[1] + red[2] + red[3]);
    int p = __builtin_amdgcn_cvt_pk_fp8_f32(v.x * rn, v.y * rn, 0, false);
    p = __builtin_amdgcn_cvt_pk_fp8_f32(v.z * rn, v.w * rn, p, true);
    ((int*)dst)[row * 256 + tid] = p;
}

// ---------------- kernel 1: per-row mask codes ------------------------------
__global__ __launch_bounds__(256) void key_kernel(
        const int* __restrict__ labels, const int* __restrict__ sm,
        const int* __restrict__ sp, int* __restrict__ code) {
    int i = blockIdx.x * 256 + threadIdx.x;
    if (i < NB) {
        int l = labels[i];
        code[i] = (l == 0) ? 0x40000000 : (1 + l + (sm[i] << 8) + (sp[i] << 16));
    }
}

// ------- kernel 2: fused row-sum + normalized masked weight matrix (fp8) ----
__global__ __launch_bounds__(256) void rowsumw_kernel(
        const float* __restrict__ cs, const int* __restrict__ code,
        unsigned char* __restrict__ W, float* __restrict__ flag) {
    int i = blockIdx.x;
    int ci = code[i];
    int tid = threadIdx.x;
    const float4* row = (const float4*)(cs + (size_t)i * NB);
    const int4* c4 = (const int4*)code;
    float4 v[4];
    int4 cj[4];
    float s = 0.f;
#pragma unroll
    for (int k = 0; k < 4; ++k) {
        int t = tid + k * 256;
        v[k] = row[t];
        cj[k] = c4[t];
        int j = t * 4;
        if (cj[k].x == ci && j + 0 != i) s += v[k].x;
        if (cj[k].y == ci && j + 1 != i) s += v[k].y;
        if (cj[k].z == ci && j + 2 != i) s += v[k].z;
        if (cj[k].w == ci && j + 3 != i) s += v[k].w;
    }
    for (int off = 1; off < 64; off <<= 1) s += __shfl_xor(s, off);
    __shared__ float red[4];
    int lane = tid & 63, w = tid >> 6;
    if (lane == 0) red[w] = s;
    __syncthreads();
    float tot = red[0] + red[1] + red[2] + red[3];
    float inv = (tot > 0.f) ? 1.f / tot : 0.f;
#pragma unroll
    for (int k = 0; k < 4; ++k) {
        int t = tid + k * 256;
        int j = t * 4;
        float f0 = (cj[k].x == ci && j + 0 != i) ? v[k].x * inv : 0.f;
        float f1 = (cj[k].y == ci && j + 1 != i) ? v[k].y * inv : 0.f;
        float f2 = (cj[k].z == ci && j + 2 != i) ? v[k].z * inv : 0.f;
        float f3 = (cj[k].w == ci && j + 3 != i) ? v[k].w * inv : 0.f;
        int p = __builtin_amdgcn_cvt_pk_fp8_f32(f0, f1, 0, false);
        p = __builtin_amdgcn_cvt_pk_fp8_f32(f2, f3, p, true);
        ((int*)W)[((size_t)i * NB + j) >> 2] = p;
    }
    if (tid == 0) flag[i] = (tot > 0.f) ? 1.f : 0.f;
}

// ------- kernel 2b: in-place symmetrize W -> Wsym = W + W^T (fp8) -----------
__global__ __launch_bounds__(256) void symw_kernel(unsigned char* __restrict__ W) {
    __shared__ unsigned char Ta[64][80], Tb[64][80];
    int b = blockIdx.x;
    int ti = 0, t = b;
    while (t >= 64 - ti) { t -= 64 - ti; ++ti; }
    int tj = ti + t;
    size_t ra = (size_t)ti * 64, rb = (size_t)tj * 64;
    int tid = threadIdx.x;
    int r = tid >> 2, c0 = (tid & 3) * 16;
    int4 a0 = *(const int4*)&W[(ra + r) * NB + rb + c0];
    int4 b0 = *(const int4*)&W[(rb + r) * NB + ra + c0];
    *(int4*)&Ta[r][c0] = a0;
    *(int4*)&Tb[r][c0] = b0;
    __syncthreads();
    unsigned char oa[16], ob[16];
#pragma unroll
    for (int c = 0; c < 16; c += 2) {
        int cc = c0 + c;
        float a_lo = fp82f(Ta[r][cc])     + fp82f(Tb[cc][r]);
        float a_hi = fp82f(Ta[r][cc + 1]) + fp82f(Tb[cc + 1][r]);
        float b_lo = fp82f(Tb[r][cc])     + fp82f(Ta[cc][r]);
        float b_hi = fp82f(Tb[r][cc + 1]) + fp82f(Ta[cc + 1][r]);
        int pa = __builtin_amdgcn_cvt_pk_fp8_f32(a_lo, a_hi, 0, false);
        int pb = __builtin_amdgcn_cvt_pk_fp8_f32(b_lo, b_hi, 0, false);
        oa[c] = (unsigned char)(pa & 0xff); oa[c + 1] = (unsigned char)((pa >> 8) & 0xff);
        ob[c] = (unsigned char)(pb & 0xff); ob[c + 1] = (unsigned char)((pb >> 8) & 0xff);
    }
    *(int4*)&W[(ra + r) * NB + rb + c0] = *(int4*)&oa[0];
    *(int4*)&W[(rb + r) * NB + ra + c0] = *(int4*)&ob[0];
}

// ---------------- kernel 3: fused fp8 256x256-tile GEMM + loss epilogue -----
// 528 blocks (XCD-chunked 8*66):
//   b < 256: cross S1 = Mf Pf^T, 2x2-supertiled 16x16 grid (1MB/supertile).
//   b >= 256: symmetric (Mf then Pf), upper-tri 136 each.
// 512 threads = 8 waves (2 wm x 4 wn), wave tile 128x64, acc[8][4]=128 AGPR.
// fp8 operands keep live arch regs ~100 <= the 128-arch cap the allocator
// imposes alongside a 128-AGPR acc (bf16 variants R4/5/6/9 needed ~150+ and
// spilled; fp8 R14 measured 104). Arithmetic intensity 256 FLOP/B-staged
// (4x the 64^2 structure) -> staged bytes drop to 270 MB total.
// K loop: 16 tiles BK=64, THREE 32KB buffers, depth-2, counted vmcnt(4),
// one barrier per step (R14-proven skeleton). Tail: Wsym 256x256 fp8 tile
// (64KB) prefetched in two 32KB halves into freed buffers.
__global__ __launch_bounds__(512) void mega_gemm(
        const unsigned char* __restrict__ Mf, const unsigned char* __restrict__ Pf,
        const unsigned char* __restrict__ Wg,
        float* __restrict__ outs) {
    __shared__ char smem[98304] __attribute__((aligned(16)));

    int tid = threadIdx.x;
    int lane = tid & 63, w = tid >> 6;      // w: 0..7
    int wm = w >> 2, wn = w & 3;            // 2x4 wave grid
    int lr = lane & 15, lg = lane >> 4;

    // ---- block decode ----
    int b = (blockIdx.x & 7) * 66 + (blockIdx.x >> 3);
    int bi, bj, mode;
    const unsigned char *A, *Bm;
    if (b < 256) {
        int st = b >> 2;                    // supertile 0..63 (8x8 grid)
        int sb = b & 3;                     // 2x2 within supertile
        bi = (st >> 3) * 2 + (sb >> 1);
        bj = (st & 7) * 2 + (sb & 1);
        A = Mf; Bm = Pf; mode = 0;
    } else {
        int s = b - 256;
        int md = (s >= 136) ? 1 : 0;
        s -= md * 136;
        bi = 0;
        while (s >= 16 - bi) { s -= 16 - bi; ++bi; }
        bj = bi + s;
        A = md ? Pf : Mf; Bm = A;
        mode = 1 + md;
    }
    bool offdiag = (bi != bj);
    size_t rowBase = (size_t)bi * 256;
    size_t colBase = (size_t)bj * 256;
    float* rowTgt = outs + ((mode == 0) ? 0 : (mode == 1) ? 8192 : 12288);
    float* colTgt = (mode == 0) ? (outs + 4096) : rowTgt;

    // ---- staging addresses: 64B fp8 rows, 4 lanes/row, pre-swizzled chunk --
    int sr = lane >> 2;                        // row 0..15 within 1KB unit
    int scs = (lane & 3) ^ (sr & 3) ^ ((sr >> 2) & 3);   // 16B chunk
    const unsigned char* gA = A + (rowBase + w * 32 + sr) * ND + scs * 16;
    const unsigned char* gB = Bm + (colBase + w * 32 + sr) * ND + scs * 16;

    f32x4 acc[8][4] = {};

    // per tile: A 256x64B (16KB) + B 256x64B (16KB); 4 x 1KB units per wave
#define STAGE(bufi, t) {                                                    \
        int k0_ = (t) * 64;                                                 \
        char* baseA_ = smem + (bufi) * 32768;                               \
        char* baseB_ = baseA_ + 16384;                                      \
        gload16(gA + k0_,                   baseA_ + (w * 2    ) * 1024);   \
        gload16(gA + (size_t)16 * ND + k0_, baseA_ + (w * 2 + 1) * 1024);   \
        gload16(gB + k0_,                   baseB_ + (w * 2    ) * 1024);   \
        gload16(gB + (size_t)16 * ND + k0_, baseB_ + (w * 2 + 1) * 1024);   \
    }
// Wsym half-tile staging: 32KB = 128 local rows x 256B; 4 x 1KB units/wave
#define STAGEW(dst, rbase) {                                                \
        _Pragma("unroll")                                                   \
        for (int c = 0; c < 4; ++c) {                                       \
            int q_ = w * 4 + c;                       /* 0..31 */           \
            int swl_ = 4 * q_ + (lane >> 4);          /* local row 0..127 */\
            int gch_ = (lane & 15) ^ (swl_ & 7);      /* src pre-swizzle */ \
            gload16(Wg + ((rbase) + swl_) * (size_t)NB + colBase + gch_ * 16,\
                    (dst) + q_ * 1024);                                     \
        }                                                                   \
    }
#define COMPUTE(bufi) {                                                     \
        const unsigned char* sA = (const unsigned char*)(smem + (bufi) * 32768); \
        const unsigned char* sB = sA + 16384;                               \
        int rx = (lr & 3) ^ ((lr >> 2) & 3);                                \
        _Pragma("unroll")                                                   \
        for (int ks = 0; ks < 2; ++ks) {                                    \
            int cp = (((ks * 2) + (lg >> 1)) ^ rx) * 16 + (lg & 1) * 8;     \
            long bv[4];                                                     \
            _Pragma("unroll")                                               \
            for (int n = 0; n < 4; ++n)                                     \
                bv[n] = *(const long*)&sB[(wn * 64 + n * 16 + lr) * 64 + cp]; \
            _Pragma("unroll")                                               \
            for (int mh = 0; mh < 2; ++mh) {                                \
                long av[4];                                                 \
                _Pragma("unroll")                                           \
                for (int i = 0; i < 4; ++i)                                 \
                    av[i] = *(const long*)&sA[(wm * 128 + (mh * 4 + i) * 16 + lr) * 64 + cp]; \
                _Pragma("unroll")                                           \
                for (int i = 0; i < 4; ++i)                                 \
                    _Pragma("unroll")                                       \
                    for (int n = 0; n < 4; ++n)                             \
                        acc[mh * 4 + i][n] = __builtin_amdgcn_mfma_f32_16x16x32_fp8_fp8( \
                            av[i], bv[n], acc[mh * 4 + i][n], 0, 0, 0);     \
            }                                                               \
        }                                                                   \
    }
#define BAR __builtin_amdgcn_s_barrier()

    // depth-2 lockstep pipeline over 3 buffers; tile t in buffer t%3.
    STAGE(0, 0); STAGE(1, 1);                       // 8 outstanding
    asm volatile("s_waitcnt vmcnt(4)" ::: "memory"); BAR;   // tile 0 ready
    for (int t = 0; t < 14; ++t) {
        STAGE((t + 2) % 3, t + 2);    // overwrites buf computed at t-1 (safe)
        COMPUTE(t % 3);
        asm volatile("s_waitcnt vmcnt(4)" ::: "memory"); BAR;  // tile t+1 ready
    }
    // staged through 15 (buf0); tile 14 (buf2) ready; buf1 free.
    STAGEW(smem + 32768, rowBase);                  // Wh1 -> buf1 (+4 -> 8)
    COMPUTE(2);                                     // tile 14
    BAR;                                            // all waves done with buf2
    STAGEW(smem + 65536, rowBase + 128);            // Wh2 -> buf2 (+4 -> 12)
    asm volatile("s_waitcnt vmcnt(8)" ::: "memory"); BAR;   // tile 15 ready
    COMPUTE(0);                                     // tile 15
    asm volatile("s_waitcnt vmcnt(0)" ::: "memory"); BAR;   // W halves ready
#undef STAGE
#undef STAGEW
#undef COMPUTE
#undef BAR

    // ---- epilogue: Wsym tile, half selected by wm (rows wm*128..+127) ----
    const unsigned char* wl = (const unsigned char*)smem + 32768 + wm * 32768;
    float d1 = 0.f;
    float cexp[4] = {0.f, 0.f, 0.f, 0.f};

#pragma unroll
    for (int m = 0; m < 8; ++m) {
        float rexp[4] = {0.f, 0.f, 0.f, 0.f};
#pragma unroll
        for (int n = 0; n < 4; ++n) {
            int jl = wn * 64 + n * 16 + lr;         // 0..255
#pragma unroll
            for (int r = 0; r < 4; ++r) {
                int rl = m * 16 + lg * 4 + r;       // local row 0..127
                float sim = acc[m][n][r] * INV_T;
                float e = __expf(sim - INV_T);
                rexp[r] += e;
                cexp[n] += e;
                int ck = (jl >> 4) ^ (rl & 7);
                d1 += fp82f(wl[rl * 256 + ck * 16 + (jl & 15)]) * sim;
            }
        }
#pragma unroll
        for (int r = 0; r < 4; ++r) {
            float v = rexp[r];
            v += __shfl_xor(v, 1); v += __shfl_xor(v, 2);
            v += __shfl_xor(v, 4); v += __shfl_xor(v, 8);
            if (lr == 0)
                atomicAdd(&rowTgt[rowBase + wm * 128 + m * 16 + lg * 4 + r], v);
        }
    }

    // col-exp sums: cross always; symmetric only for offdiag tiles
    if (mode == 0 || offdiag) {
#pragma unroll
        for (int n = 0; n < 4; ++n) {
            float v = cexp[n];
            v += __shfl_xor(v, 16); v += __shfl_xor(v, 32);
            if (lg == 0)
                atomicAdd(&colTgt[colBase + wn * 64 + n * 16 + lr], v);
        }
    }

    // weighted dot: Wsym covers (i,j)+(j,i). diag sym tile counts half.
    float dtot = (mode != 0 && !offdiag) ? 0.5f * d1 : d1;
    for (int off = 32; off; off >>= 1) dtot += __shfl_xor(dtot, off);
    if (lane == 0) {
        float* dots = outs + 16384;
        if (mode == 0) atomicAdd(&dots[0], dtot);
        else           atomicAdd(&dots[1 + mode], dtot);
    }
}

// ---------------- kernel 4: finalize --------------------------------------
__global__ __launch_bounds__(256) void finalize_kernel(
        const float* __restrict__ outs, const float* __restrict__ flag,
        float* __restrict__ out) {
    const float* rowsum1 = outs;
    const float* colsum1 = outs + 4096;
    const float* rowsum3 = outs + 8192;
    const float* rowsum4 = outs + 12288;
    const float* dots = outs + 16384;
    int tid = threadIdx.x;
    float l = 0.f;
    for (int i = tid; i < NB; i += 256) {
        if (flag[i] != 0.f) {
            l += 4.f * INV_T + logf(rowsum1[i]) + logf(colsum1[i]) +
                 logf(rowsum3[i]) + logf(rowsum4[i]);
        }
    }
    for (int off = 32; off; off >>= 1) l += __shfl_down(l, off);
    __shared__ float red[4];
    int lane = tid & 63, w = tid >> 6;
    if (lane == 0) red[w] = l;
    __syncthreads();
    if (tid == 0) {
        float L = red[0] + red[1] + red[2] + red[3];
        float dt = dots[0] + dots[1] + dots[2] + dots[3];
        out[0] = (L - dt) / (4.0f * (float)NB);
    }
}

extern "C" void kernel_launch(void* const* d_in, const int* in_sizes, int n_in,
                              void* d_out, int out_size, void* d_ws, size_t ws_size,
                              hipStream_t stream) {
    const float* M = (const float*)d_in[0];
    const float* P = (const float*)d_in[1];
    const int* labels = (const int*)d_in[2];
    const int* sm = (const int*)d_in[3];
    const int* sp = (const int*)d_in[4];
    const float* cs = (const float*)d_in[5];
    float* out = (float*)d_out;

    char* ws = (char*)d_ws;
    unsigned char* Mf = (unsigned char*)ws;                                // 4 MB
    unsigned char* Pf = (unsigned char*)(ws + (size_t)4 * 1024 * 1024);    // 4 MB
    unsigned char* W = (unsigned char*)(ws + (size_t)16 * 1024 * 1024);    // 16 MB
    char* p = ws + (size_t)48 * 1024 * 1024;
    int* code = (int*)p;    p += 16384;
    float* flag = (float*)p; p += 16384;
    float* outs = (float*)p;   // rowsum1|colsum1|rowsum3|rowsum4|dots

    hipMemsetAsync(outs, 0, 4 * 16384 + 256, stream);

    norm_kernel<<<2 * NB, 256, 0, stream>>>(M, P, Mf, Pf);
    key_kernel<<<NB / 256, 256, 0, stream>>>(labels, sm, sp, code);
    rowsumw_kernel<<<NB, 256, 0, stream>>>(cs, code, W, flag);
    symw_kernel<<<2080, 256, 0, stream>>>(W);

    mega_gemm<<<528, 512, 0, stream>>>(Mf, Pf, W, outs);

    finalize_kernel<<<1, 256, 0, stream>>>(outs, flag, out);
}